// Round 3
// baseline (297.021 us; speedup 1.0000x reference)
//
#include <hip/hip_runtime.h>
#include <hip/hip_bf16.h>

#define N 8192
#define Dd 128

typedef short short8 __attribute__((ext_vector_type(8)));
typedef float floatx4 __attribute__((ext_vector_type(4)));

// round-to-nearest-even fp32 -> bf16 (no NaN in inputs)
static __device__ inline unsigned short f2bf(float f) {
    unsigned int u = __float_as_uint(f);
    return (unsigned short)((u + 0x7fffu + ((u >> 16) & 1u)) >> 16);
}
static __device__ inline float bf2f(unsigned short b) {
    return __uint_as_float(((unsigned int)b) << 16);
}

// Fully fused: one kernel. Each 128x128-tile block loads its fp32 row-panels
// of z directly, converts to bf16 in-register (computing row norms of the
// ROUNDED values so the gram diagonal cancels), stages swizzled bf16 panels
// in LDS, runs the K=128 MFMA sweep, and stores exp(-max(d2,0)) directly
// from the accumulator C-layout (R1-style scattered dword stores -- L2
// write-back merges the 64B half-lines; the R2 LDS-transpose epilogue
// measured 30us SLOWER from the extra syncs + LDS traffic).
__global__ __launch_bounds__(256, 2) void pairsim_kernel(const float* __restrict__ z,
                                                         float* __restrict__ out) {
    __shared__ unsigned short lA[128 * 128];   // 32 KB bf16 panel A (swizzled)
    __shared__ unsigned short lB[128 * 128];   // 32 KB bf16 panel B (swizzled)
    __shared__ float sqA[128], sqB[128];       // row norms of rounded panels

    int bx = blockIdx.x, by = blockIdx.y;
    int colBase = bx * 128, rowBase = by * 128;
    int t  = threadIdx.x;
    int r0 = t >> 4, cg = t & 15;   // 16 rows x 16 bf16-chunks (16B) per pass

    const float4* gA = (const float4*)(z + (size_t)rowBase * Dd);
    const float4* gB = (const float4*)(z + (size_t)colBase * Dd);

    float sA[8], sB[8];
    #pragma unroll
    for (int i = 0; i < 8; i++) {
        int row = r0 + i * 16;
        float4 a0 = gA[row * 32 + 2 * cg];
        float4 a1 = gA[row * 32 + 2 * cg + 1];
        float fs[8] = {a0.x, a0.y, a0.z, a0.w, a1.x, a1.y, a1.z, a1.w};
        float s = 0.f;
        short8 pk;
        #pragma unroll
        for (int e = 0; e < 8; e++) {
            unsigned short h = f2bf(fs[e]);
            float fr = bf2f(h);
            s += fr * fr;
            pk[e] = (short)h;
        }
        *(short8*)&lA[row * 128 + ((cg ^ r0) * 8)] = pk;
        sA[i] = s;
    }
    #pragma unroll
    for (int i = 0; i < 8; i++) {
        int row = r0 + i * 16;
        float4 b0 = gB[row * 32 + 2 * cg];
        float4 b1 = gB[row * 32 + 2 * cg + 1];
        float fs[8] = {b0.x, b0.y, b0.z, b0.w, b1.x, b1.y, b1.z, b1.w};
        float s = 0.f;
        short8 pk;
        #pragma unroll
        for (int e = 0; e < 8; e++) {
            unsigned short h = f2bf(fs[e]);
            float fr = bf2f(h);
            s += fr * fr;
            pk[e] = (short)h;
        }
        *(short8*)&lB[row * 128 + ((cg ^ r0) * 8)] = pk;
        sB[i] = s;
    }

    // Row-norm reduction: the 16 lanes sharing r0 are a contiguous 16-lane
    // group (t = r0*16 + cg), so width-16 shuffles reduce within the group.
    #pragma unroll
    for (int i = 0; i < 8; i++) {
        float s = sA[i];
        #pragma unroll
        for (int off = 8; off > 0; off >>= 1) s += __shfl_down(s, off, 16);
        if (cg == 0) sqA[r0 + i * 16] = s;
        float sb = sB[i];
        #pragma unroll
        for (int off = 8; off > 0; off >>= 1) sb += __shfl_down(sb, off, 16);
        if (cg == 0) sqB[r0 + i * 16] = sb;
    }
    __syncthreads();

    int w = t >> 6, lane = t & 63;
    int wr = (w >> 1) * 64, wc = (w & 1) * 64;   // 2x2 waves -> 64x64 each
    int m = lane & 15, quad = lane >> 4;

    floatx4 zero = {0.f, 0.f, 0.f, 0.f};
    floatx4 acc[4][4];
    #pragma unroll
    for (int i = 0; i < 4; i++)
        #pragma unroll
        for (int j = 0; j < 4; j++) acc[i][j] = zero;

    #pragma unroll
    for (int ks = 0; ks < 4; ks++) {
        short8 af[4], bfr[4];
        int c = ks * 4 + quad;      // 16B chunk index along K
        #pragma unroll
        for (int i = 0; i < 4; i++)
            af[i] = *(const short8*)&lA[(wr + i * 16 + m) * 128 + ((c ^ m) * 8)];
        #pragma unroll
        for (int j = 0; j < 4; j++)
            bfr[j] = *(const short8*)&lB[(wc + j * 16 + m) * 128 + ((c ^ m) * 8)];
        #pragma unroll
        for (int i = 0; i < 4; i++)
            #pragma unroll
            for (int j = 0; j < 4; j++)
                acc[i][j] = __builtin_amdgcn_mfma_f32_16x16x32_bf16(af[i], bfr[j], acc[i][j], 0, 0, 0);
    }

    // Epilogue: exp(-max(sq_r + sq_c - 2g, 0)) straight from C-layout
    // (col = lane&15, row = quad*4 + reg), nontemporal dword stores.
    #pragma unroll
    for (int j = 0; j < 4; j++) {
        int cl = wc + j * 16 + m;
        float sc = sqB[cl];
        #pragma unroll
        for (int i = 0; i < 4; i++) {
            #pragma unroll
            for (int r = 0; r < 4; r++) {
                int rl = wr + i * 16 + quad * 4 + r;
                float sr = sqA[rl];
                float g = acc[i][j][r];
                float e = fminf(2.0f * g - sr - sc, 0.0f);
                __builtin_nontemporal_store(__expf(e),
                    &out[(size_t)(rowBase + rl) * N + colBase + cl]);
            }
        }
    }
}

extern "C" void kernel_launch(void* const* d_in, const int* in_sizes, int n_in,
                              void* d_out, int out_size, void* d_ws, size_t ws_size,
                              hipStream_t stream) {
    const float* z = (const float*)d_in[0];
    float* out = (float*)d_out;
    pairsim_kernel<<<dim3(64, 64), 256, 0, stream>>>(z, out);
}

// Round 4
// 274.809 us; speedup vs baseline: 1.0808x; 1.0808x over previous
//
#include <hip/hip_runtime.h>
#include <hip/hip_bf16.h>

#define N 8192
#define Dd 128

typedef short short8 __attribute__((ext_vector_type(8)));
typedef float floatx4 __attribute__((ext_vector_type(4)));

// round-to-nearest-even fp32 -> bf16 (no NaN in inputs)
static __device__ inline unsigned short f2bf(float f) {
    unsigned int u = __float_as_uint(f);
    return (unsigned short)((u + 0x7fffu + ((u >> 16) & 1u)) >> 16);
}
static __device__ inline float bf2f(unsigned short b) {
    return __uint_as_float(((unsigned int)b) << 16);
}

// One wave per row: convert to bf16, store, and compute row norm of the
// *rounded* values so the gram diagonal cancels exactly.
__global__ __launch_bounds__(256) void prep_kernel(const float* __restrict__ z,
                                                   unsigned short* __restrict__ zb,
                                                   float* __restrict__ sq) {
    int row  = blockIdx.x * 4 + (threadIdx.x >> 6);
    int lane = threadIdx.x & 63;
    float2 v = ((const float2*)z)[row * 64 + lane];
    unsigned short b0 = f2bf(v.x);
    unsigned short b1 = f2bf(v.y);
    float f0 = bf2f(b0), f1 = bf2f(b1);
    ushort2 st; st.x = b0; st.y = b1;
    ((ushort2*)zb)[row * 64 + lane] = st;
    float s = f0 * f0 + f1 * f1;
    #pragma unroll
    for (int off = 32; off > 0; off >>= 1) s += __shfl_down(s, off, 64);
    if (lane == 0) sq[row] = s;
}

// R1 structure (measured best: ~76us kernel time) with ONE change:
// 512 threads/block (8 waves, 2x4 grid of 64x32 sub-tiles) -> 4 waves/SIMD
// instead of 2, to hide epilogue exp/store latency behind the HBM write
// stream. Direct scattered dword stores (L2 write-back merges half-lines;
// nt-store and LDS-transpose epilogues both measured slower, R2/R3).
__global__ __launch_bounds__(512, 4) void pairsim_kernel(const unsigned short* __restrict__ zb,
                                                         const float* __restrict__ sq,
                                                         float* __restrict__ out) {
    __shared__ unsigned short lA[128 * 128];   // 32 KB swizzled bf16 panel
    __shared__ unsigned short lB[128 * 128];   // 32 KB swizzled bf16 panel

    int bx = blockIdx.x, by = blockIdx.y;
    int colBase = bx * 128, rowBase = by * 128;
    int t  = threadIdx.x;
    int r0 = t >> 4, cg = t & 15;   // 32 rows x 16 chunks per pass, 4 passes

    const uint4* gA = (const uint4*)(zb + (size_t)rowBase * Dd);
    const uint4* gB = (const uint4*)(zb + (size_t)colBase * Dd);
    uint4 va[4], vb[4];
    #pragma unroll
    for (int i = 0; i < 4; i++) va[i] = gA[(r0 + i * 32) * 16 + cg];
    #pragma unroll
    for (int i = 0; i < 4; i++) vb[i] = gB[(r0 + i * 32) * 16 + cg];

    int scg = ((cg ^ (r0 & 15)) * 8);   // swizzled chunk offset (elements)
    #pragma unroll
    for (int i = 0; i < 4; i++) *(uint4*)&lA[(r0 + i * 32) * 128 + scg] = va[i];
    #pragma unroll
    for (int i = 0; i < 4; i++) *(uint4*)&lB[(r0 + i * 32) * 128 + scg] = vb[i];
    __syncthreads();

    int w = t >> 6, lane = t & 63;
    int wr = (w >> 2) * 64, wc = (w & 3) * 32;   // 2x4 waves -> 64x32 each
    int m = lane & 15, quad = lane >> 4;

    floatx4 zero = {0.f, 0.f, 0.f, 0.f};
    floatx4 acc[4][2];
    #pragma unroll
    for (int i = 0; i < 4; i++)
        #pragma unroll
        for (int j = 0; j < 2; j++) acc[i][j] = zero;

    #pragma unroll
    for (int ks = 0; ks < 4; ks++) {
        short8 af[4], bfr[2];
        int c = ks * 4 + quad;      // 16B chunk index along K
        #pragma unroll
        for (int i = 0; i < 4; i++)
            af[i] = *(const short8*)&lA[(wr + i * 16 + m) * 128 + ((c ^ m) * 8)];
        #pragma unroll
        for (int j = 0; j < 2; j++)
            bfr[j] = *(const short8*)&lB[(wc + j * 16 + m) * 128 + ((c ^ m) * 8)];
        #pragma unroll
        for (int i = 0; i < 4; i++)
            #pragma unroll
            for (int j = 0; j < 2; j++)
                acc[i][j] = __builtin_amdgcn_mfma_f32_16x16x32_bf16(af[i], bfr[j], acc[i][j], 0, 0, 0);
    }

    // Epilogue: exp(-max(sq_r + sq_c - 2g, 0)) straight from C-layout
    // (col = lane&15, row = quad*4 + reg), plain dword stores.
    #pragma unroll
    for (int j = 0; j < 2; j++) {
        int col = colBase + wc + j * 16 + m;
        float sc = sq[col];
        #pragma unroll
        for (int i = 0; i < 4; i++) {
            #pragma unroll
            for (int r = 0; r < 4; r++) {
                int row = rowBase + wr + i * 16 + quad * 4 + r;
                float sr = sq[row];
                float g = acc[i][j][r];
                float e = fminf(2.0f * g - sr - sc, 0.0f);
                out[(size_t)row * N + col] = __expf(e);
            }
        }
    }
}

extern "C" void kernel_launch(void* const* d_in, const int* in_sizes, int n_in,
                              void* d_out, int out_size, void* d_ws, size_t ws_size,
                              hipStream_t stream) {
    const float* z = (const float*)d_in[0];
    unsigned short* zb = (unsigned short*)d_ws;                       // 2 MB bf16 copy
    float* sqv = (float*)((char*)d_ws + (size_t)N * Dd * sizeof(unsigned short)); // 32 KB norms
    float* out = (float*)d_out;

    prep_kernel<<<N / 4, 256, 0, stream>>>(z, zb, sqv);
    pairsim_kernel<<<dim3(64, 64), 512, 0, stream>>>(zb, sqv, out);
}

// Round 5
// 260.057 us; speedup vs baseline: 1.1421x; 1.0567x over previous
//
#include <hip/hip_runtime.h>
#include <hip/hip_bf16.h>

#define N 8192
#define Dd 128

typedef short short8 __attribute__((ext_vector_type(8)));
typedef float floatx4 __attribute__((ext_vector_type(4)));

// round-to-nearest-even fp32 -> bf16 (no NaN in inputs)
static __device__ inline unsigned short f2bf(float f) {
    unsigned int u = __float_as_uint(f);
    return (unsigned short)((u + 0x7fffu + ((u >> 16) & 1u)) >> 16);
}
static __device__ inline float bf2f(unsigned short b) {
    return __uint_as_float(((unsigned int)b) << 16);
}

// One wave per row: convert to bf16, store, and compute row norm of the
// *rounded* values so the gram diagonal cancels exactly.
__global__ __launch_bounds__(256) void prep_kernel(const float* __restrict__ z,
                                                   unsigned short* __restrict__ zb,
                                                   float* __restrict__ sq) {
    int row  = blockIdx.x * 4 + (threadIdx.x >> 6);
    int lane = threadIdx.x & 63;
    float2 v = ((const float2*)z)[row * 64 + lane];
    unsigned short b0 = f2bf(v.x);
    unsigned short b1 = f2bf(v.y);
    float f0 = bf2f(b0), f1 = bf2f(b1);
    ushort2 st; st.x = b0; st.y = b1;
    ((ushort2*)zb)[row * 64 + lane] = st;
    float s = f0 * f0 + f1 * f1;
    #pragma unroll
    for (int off = 32; off > 0; off >>= 1) s += __shfl_down(s, off, 64);
    if (lane == 0) sq[row] = s;
}

// R1 structure, ONE change vs R1: 64x64 tiles (16 KB panels, 32 KB LDS)
// -> 5 blocks/CU instead of 2. Within-block phases are serialized by the
// staging barrier (R4 showed intra-block waves don't pipeline); only
// independent resident blocks overlap staging/epilogue with the HBM write
// stream, so more blocks/CU = deeper phase pipelining. Stores stay direct
// scattered dwords (R2 LDS-transpose and R3 nt-stores both regressed),
// with j innermost so both 64B halves of a 128B line issue back-to-back.
__global__ __launch_bounds__(256, 4) void pairsim_kernel(const unsigned short* __restrict__ zb,
                                                         const float* __restrict__ sq,
                                                         float* __restrict__ out) {
    __shared__ unsigned short lA[64 * 128];   // 16 KB swizzled bf16 panel
    __shared__ unsigned short lB[64 * 128];   // 16 KB swizzled bf16 panel

    int bx = blockIdx.x, by = blockIdx.y;
    int colBase = bx * 64, rowBase = by * 64;
    int t  = threadIdx.x;
    int r0 = t >> 4, cg = t & 15;   // 16 rows x 16 chunks per pass, 4 passes

    const uint4* gA = (const uint4*)(zb + (size_t)rowBase * Dd);
    const uint4* gB = (const uint4*)(zb + (size_t)colBase * Dd);
    uint4 va[4], vb[4];
    #pragma unroll
    for (int i = 0; i < 4; i++) va[i] = gA[(r0 + i * 16) * 16 + cg];
    #pragma unroll
    for (int i = 0; i < 4; i++) vb[i] = gB[(r0 + i * 16) * 16 + cg];

    int scg = ((cg ^ r0) * 8);      // swizzled chunk offset (elements)
    #pragma unroll
    for (int i = 0; i < 4; i++) *(uint4*)&lA[(r0 + i * 16) * 128 + scg] = va[i];
    #pragma unroll
    for (int i = 0; i < 4; i++) *(uint4*)&lB[(r0 + i * 16) * 128 + scg] = vb[i];
    __syncthreads();

    int w = t >> 6, lane = t & 63;
    int wr = (w >> 1) * 32, wc = (w & 1) * 32;   // 2x2 waves -> 32x32 each
    int m = lane & 15, quad = lane >> 4;

    floatx4 zero = {0.f, 0.f, 0.f, 0.f};
    floatx4 acc[2][2];
    #pragma unroll
    for (int i = 0; i < 2; i++)
        #pragma unroll
        for (int j = 0; j < 2; j++) acc[i][j] = zero;

    #pragma unroll
    for (int ks = 0; ks < 4; ks++) {
        short8 af[2], bfr[2];
        int c = ks * 4 + quad;      // 16B chunk index along K
        #pragma unroll
        for (int i = 0; i < 2; i++)
            af[i] = *(const short8*)&lA[(wr + i * 16 + m) * 128 + ((c ^ m) * 8)];
        #pragma unroll
        for (int j = 0; j < 2; j++)
            bfr[j] = *(const short8*)&lB[(wc + j * 16 + m) * 128 + ((c ^ m) * 8)];
        #pragma unroll
        for (int i = 0; i < 2; i++)
            #pragma unroll
            for (int j = 0; j < 2; j++)
                acc[i][j] = __builtin_amdgcn_mfma_f32_16x16x32_bf16(af[i], bfr[j], acc[i][j], 0, 0, 0);
    }

    // Epilogue: exp(-max(sq_r + sq_c - 2g, 0)) straight from C-layout
    // (col = lane&15, row = quad*4 + reg). j innermost: both halves of a
    // 128B line issue consecutively.
    #pragma unroll
    for (int i = 0; i < 2; i++) {
        #pragma unroll
        for (int r = 0; r < 4; r++) {
            int row = rowBase + wr + i * 16 + quad * 4 + r;
            float sr = sq[row];
            #pragma unroll
            for (int j = 0; j < 2; j++) {
                int col = colBase + wc + j * 16 + m;
                float sc = sq[col];
                float g = acc[i][j][r];
                float e = fminf(2.0f * g - sr - sc, 0.0f);
                out[(size_t)row * N + col] = __expf(e);
            }
        }
    }
}

extern "C" void kernel_launch(void* const* d_in, const int* in_sizes, int n_in,
                              void* d_out, int out_size, void* d_ws, size_t ws_size,
                              hipStream_t stream) {
    const float* z = (const float*)d_in[0];
    unsigned short* zb = (unsigned short*)d_ws;                       // 2 MB bf16 copy
    float* sqv = (float*)((char*)d_ws + (size_t)N * Dd * sizeof(unsigned short)); // 32 KB norms
    float* out = (float*)d_out;

    prep_kernel<<<N / 4, 256, 0, stream>>>(z, zb, sqv);
    pairsim_kernel<<<dim3(128, 128), 256, 0, stream>>>(zb, sqv, out);
}